// Round 4
// baseline (968.883 us; speedup 1.0000x reference)
//
#include <hip/hip_runtime.h>
#include <hip/hip_bf16.h>
#include <math.h>

#define TT 8192
#define HD 1024
#define FHD 4096
#define NE 8
#define TMAX 72

typedef short s16x8 __attribute__((ext_vector_type(8)));
typedef float f32x4 __attribute__((ext_vector_type(4)));
using bf16 = __hip_bfloat16;
typedef unsigned int u32;

// workspace layout (bytes)
#define OFF_COUNTS 0
#define OFF_CURSOR 64
#define OFF_OFFS   128
#define OFF_E0     256
#define OFF_E1     (OFF_E0 + 4*TT)
#define OFF_W0     (OFF_E1 + 4*TT)
#define OFF_W1     (OFF_W0 + 4*TT)
#define OFF_S0     (OFF_W1 + 4*TT)
#define OFF_S1     (OFF_S0 + 4*TT)
#define OFF_TID    (OFF_S1 + 4*TT)
#define OFF_TW     (OFF_TID + 8*TT)
#define OFF_TMR    (OFF_TW + 8*TT)
#define OFF_TME    (OFF_TMR + 4*144)
#define OFF_TMN    (OFF_TME + 4*144)
#define OFF_XBF    (OFF_TMN + 64)
#define OFF_W1T    (OFF_XBF + 2*TT*HD)
#define OFF_W2T    (OFF_W1T + 2*NE*HD*FHD)
#define OFF_HMID   (OFF_W2T + 2*NE*HD*FHD)
#define OFF_YS     (OFF_HMID + (size_t)2*(2*TT)*FHD)

__device__ __forceinline__ void gload_lds16(const void* g, void* l) {
    __builtin_amdgcn_global_load_lds(
        (const __attribute__((address_space(1))) u32*)g,
        (__attribute__((address_space(3))) u32*)l, 16, 0, 0);
}

__global__ __launch_bounds__(256) void cast_x_kernel(const float* __restrict__ x, bf16* __restrict__ xbf) {
    int i = (blockIdx.x * 256 + threadIdx.x) * 8;
    float4 a = *reinterpret_cast<const float4*>(&x[i]);
    float4 b = *reinterpret_cast<const float4*>(&x[i + 4]);
    bf16 h[8];
    h[0] = __float2bfloat16(a.x); h[1] = __float2bfloat16(a.y);
    h[2] = __float2bfloat16(a.z); h[3] = __float2bfloat16(a.w);
    h[4] = __float2bfloat16(b.x); h[5] = __float2bfloat16(b.y);
    h[6] = __float2bfloat16(b.z); h[7] = __float2bfloat16(b.w);
    *reinterpret_cast<uint4*>(&xbf[i]) = *reinterpret_cast<uint4*>(h);
}

// transpose+cast: out[c][r] = bf16(in[r][c]); per-expert matrices of shape [R][C].
__global__ __launch_bounds__(256) void transpose_cast_kernel(const float* __restrict__ in,
        bf16* __restrict__ out, int R, int C) {
    __shared__ float tile[64][65];
    int rt = R >> 6, ct = C >> 6;
    int e = blockIdx.x / (rt * ct);
    int rem = blockIdx.x % (rt * ct);
    int r0 = (rem / ct) << 6, c0 = (rem % ct) << 6;
    const float* ine = in + (size_t)e * R * C;
    bf16* oute = out + (size_t)e * R * C;
    int tid = threadIdx.x;
#pragma unroll
    for (int i = 0; i < 4; ++i) {
        int lin = tid + i * 256;
        int r = lin >> 4, cg = lin & 15;
        float4 v = *reinterpret_cast<const float4*>(&ine[(size_t)(r0 + r) * C + c0 + cg * 4]);
        tile[r][cg * 4 + 0] = v.x; tile[r][cg * 4 + 1] = v.y;
        tile[r][cg * 4 + 2] = v.z; tile[r][cg * 4 + 3] = v.w;
    }
    __syncthreads();
#pragma unroll
    for (int i = 0; i < 4; ++i) {
        int lin = tid + i * 256;
        int n = lin >> 4, kg = lin & 15;
        bf16 h[4];
        h[0] = __float2bfloat16(tile[kg * 4 + 0][n]);
        h[1] = __float2bfloat16(tile[kg * 4 + 1][n]);
        h[2] = __float2bfloat16(tile[kg * 4 + 2][n]);
        h[3] = __float2bfloat16(tile[kg * 4 + 3][n]);
        *reinterpret_cast<uint2*>(&oute[(size_t)(c0 + n) * R + r0 + kg * 4]) =
            *reinterpret_cast<uint2*>(h);
    }
}

__global__ __launch_bounds__(256) void router_kernel(const float* __restrict__ x,
        const float* __restrict__ rw, const float* __restrict__ rb,
        int* __restrict__ e0a, int* __restrict__ e1a,
        float* __restrict__ w0a, float* __restrict__ w1a, int* __restrict__ counts) {
    int wid = threadIdx.x >> 6, lane = threadIdx.x & 63;
    int t = blockIdx.x * 4 + wid;
    const float* xp = x + (size_t)t * HD + lane * 16;
    float xv[16];
#pragma unroll
    for (int j = 0; j < 4; ++j) {
        float4 v = *reinterpret_cast<const float4*>(&xp[j * 4]);
        xv[4 * j] = v.x; xv[4 * j + 1] = v.y; xv[4 * j + 2] = v.z; xv[4 * j + 3] = v.w;
    }
    float acc[8] = {0.f, 0.f, 0.f, 0.f, 0.f, 0.f, 0.f, 0.f};
    const float* rp = rw + (size_t)(lane * 16) * NE;
#pragma unroll
    for (int hh = 0; hh < 16; ++hh) {
        float4 r0 = *reinterpret_cast<const float4*>(&rp[hh * 8]);
        float4 r1 = *reinterpret_cast<const float4*>(&rp[hh * 8 + 4]);
        acc[0] += xv[hh] * r0.x; acc[1] += xv[hh] * r0.y;
        acc[2] += xv[hh] * r0.z; acc[3] += xv[hh] * r0.w;
        acc[4] += xv[hh] * r1.x; acc[5] += xv[hh] * r1.y;
        acc[6] += xv[hh] * r1.z; acc[7] += xv[hh] * r1.w;
    }
#pragma unroll
    for (int e = 0; e < 8; ++e) {
#pragma unroll
        for (int off = 32; off > 0; off >>= 1) acc[e] += __shfl_xor(acc[e], off, 64);
    }
    if (lane == 0) {
        float lg[8];
#pragma unroll
        for (int e = 0; e < 8; ++e) lg[e] = acc[e] + rb[e];
        int a = 0;
#pragma unroll
        for (int e = 1; e < 8; ++e) if (lg[e] > lg[a]) a = e;
        int b = (a == 0) ? 1 : 0;
#pragma unroll
        for (int e = 0; e < 8; ++e) if (e != a && e != b && lg[e] > lg[b]) b = e;
        float wa = 1.0f / (1.0f + expf(lg[b] - lg[a]));
        float wb = 1.0f / (1.0f + expf(lg[a] - lg[b]));
        e0a[t] = a; e1a[t] = b; w0a[t] = wa; w1a[t] = wb;
        atomicAdd(&counts[a], 1);
        atomicAdd(&counts[b], 1);
    }
}

// builds offsets, cursors, and the compact 256-row M-tile map (row0, expert)
__global__ void scan_offsets_kernel(const int* __restrict__ counts, int* __restrict__ offs,
        int* __restrict__ cursor, int* __restrict__ tmr, int* __restrict__ tme,
        int* __restrict__ tmn) {
    if (threadIdx.x == 0 && blockIdx.x == 0) {
        int s = 0, nt = 0;
        for (int e = 0; e < NE; ++e) {
            offs[e] = s; cursor[e] = s;
            int c = counts[e];
            for (int j = 0; j < c; j += 256) { tmr[nt] = s + j; tme[nt] = e; ++nt; }
            s += c;
        }
        offs[NE] = s;
        tmn[0] = nt;
        for (int i = nt; i < TMAX; ++i) { tmr[i] = 0; tme[i] = 0; }
    }
}

__global__ __launch_bounds__(256) void scatter_kernel(const int* __restrict__ e0a, const int* __restrict__ e1a,
        const float* __restrict__ w0a, const float* __restrict__ w1a,
        int* __restrict__ cursor, int* __restrict__ tid_arr, float* __restrict__ tw_arr,
        int* __restrict__ slot0, int* __restrict__ slot1) {
    int t = blockIdx.x * 256 + threadIdx.x;
    int s0 = atomicAdd(&cursor[e0a[t]], 1);
    tid_arr[s0] = t; tw_arr[s0] = w0a[t]; slot0[t] = s0;
    int s1 = atomicAdd(&cursor[e1a[t]], 1);
    tid_arr[s1] = t; tw_arr[s1] = w1a[t]; slot1[t] = s1;
}

// ---------------- GEMM1: 256x256 tile, BK=32, 4-buffer counted-vmcnt pipeline ----------------
// hmid[slot,:] = gelu( x[tok[slot],:] @ w1t[e]^T + b1[e] ), bf16 out
__global__ __launch_bounds__(512) void gemm1_kernel(const bf16* __restrict__ xbf, const bf16* __restrict__ w1t,
        const float* __restrict__ b1, const int* __restrict__ offs,
        const int* __restrict__ tid_arr, bf16* __restrict__ hmid,
        const int* __restrict__ tmr, const int* __restrict__ tme, const int* __restrict__ tmn) {
    __shared__ bf16 As[4 * 256 * 32];   // 64 KB
    __shared__ bf16 Bs[4 * 256 * 32];   // 64 KB
    __shared__ int toks[256];
    int nwg = gridDim.x;                 // 1152, %8==0
    int orig = blockIdx.x;
    int wg = (orig & 7) * (nwg >> 3) + (orig >> 3);
    int nt = wg / TMAX, tidx = wg % TMAX;
    if (tidx >= tmn[0]) return;
    int e = tme[tidx], row0 = tmr[tidx], s1 = offs[e + 1];
    int n0 = nt * 256;
    int t = threadIdx.x;
    if (t < 256) { int s = row0 + t; toks[t] = tid_arr[(s < s1) ? s : (s1 - 1)]; }
    __syncthreads();
    int lane = t & 63, w = t >> 6;       // 8 waves
    const bf16* w1e = w1t + (size_t)e * FHD * HD;
    // ---- staging precompute: thread t loads 16B for LDS-linear slot (row rs, elem-group g)
    int rs = t >> 2, g = t & 3;          // rs 0..127 within half
    int swz = (g ^ ((rs >> 1) & 3)) * 8; // pre-swizzled source column (elems)
    const bf16* srcA0 = xbf + (size_t)toks[rs] * HD + swz;
    const bf16* srcA1 = xbf + (size_t)toks[rs + 128] * HD + swz;
    const bf16* srcB0 = w1e + (size_t)(n0 + rs) * HD + swz;
    const bf16* srcB1 = w1e + (size_t)(n0 + rs + 128) * HD + swz;
    int dst0 = w * 512;                  // elems: wave covers rows [16w,16w+16)
    int dst1 = 4096 + w * 512;           // +128 rows
    // ---- fragment read offsets (swizzled)
    int wr = w >> 2, wc = w & 3;
    int lr = lane & 15, lk = (lane >> 4) * 8;
    int offA[8], offB[4];
#pragma unroll
    for (int m = 0; m < 8; ++m) { int row = wr * 128 + m * 16 + lr; offA[m] = row * 32 + (lk ^ (8 * ((row >> 1) & 3))); }
#pragma unroll
    for (int n = 0; n < 4; ++n) { int row = wc * 64 + n * 16 + lr; offB[n] = row * 32 + (lk ^ (8 * ((row >> 1) & 3))); }
    f32x4 acc[8][4] = {};
    // ---- prologue: stage kt = 0,1,2 (12 loads in flight)
#pragma unroll
    for (int kt = 0; kt < 3; ++kt) {
        int bo = kt * 8192, ko = kt * 32;
        gload_lds16(srcA0 + ko, &As[bo + dst0]);
        gload_lds16(srcA1 + ko, &As[bo + dst1]);
        gload_lds16(srcB0 + ko, &Bs[bo + dst0]);
        gload_lds16(srcB1 + ko, &Bs[bo + dst1]);
    }
    asm volatile("s_waitcnt vmcnt(8)" ::: "memory");
    __builtin_amdgcn_s_barrier();
    for (int kt = 0; kt < HD / 32; ++kt) {
        const bf16* Ab = &As[(kt & 3) * 8192];
        const bf16* Bb = &Bs[(kt & 3) * 8192];
        s16x8 aF[8], bF[4];
#pragma unroll
        for (int m = 0; m < 8; ++m) aF[m] = *reinterpret_cast<const s16x8*>(&Ab[offA[m]]);
#pragma unroll
        for (int n = 0; n < 4; ++n) bF[n] = *reinterpret_cast<const s16x8*>(&Bb[offB[n]]);
        int kt3 = kt + 3; if (kt3 >= HD / 32) kt3 -= HD / 32;   // wrap: lands in dead buffer
        int bo = (kt3 & 3) * 8192, ko = kt3 * 32;
        gload_lds16(srcA0 + ko, &As[bo + dst0]);
        gload_lds16(srcA1 + ko, &As[bo + dst1]);
        gload_lds16(srcB0 + ko, &Bs[bo + dst0]);
        gload_lds16(srcB1 + ko, &Bs[bo + dst1]);
        asm volatile("s_waitcnt vmcnt(8)" ::: "memory");
        __builtin_amdgcn_s_barrier();
        __builtin_amdgcn_sched_barrier(0);
        __builtin_amdgcn_s_setprio(1);
#pragma unroll
        for (int m = 0; m < 8; ++m)
#pragma unroll
            for (int n = 0; n < 4; ++n)
                acc[m][n] = __builtin_amdgcn_mfma_f32_16x16x32_bf16(aF[m], bF[n], acc[m][n], 0, 0, 0);
        __builtin_amdgcn_s_setprio(0);
        __builtin_amdgcn_sched_barrier(0);
        __builtin_amdgcn_s_barrier();
    }
    // ---- epilogue
#pragma unroll
    for (int n = 0; n < 4; ++n) {
        int col = n0 + wc * 64 + n * 16 + lr;
        float bv = b1[(size_t)e * FHD + col];
#pragma unroll
        for (int m = 0; m < 8; ++m) {
#pragma unroll
            for (int r = 0; r < 4; ++r) {
                int row = wr * 128 + m * 16 + (lane >> 4) * 4 + r;
                int slot = row0 + row;
                if (slot < s1) {
                    float v2 = acc[m][n][r] + bv;
                    v2 = 0.5f * v2 * (1.0f + erff(v2 * 0.70710678118f));
                    hmid[(size_t)slot * FHD + col] = __float2bfloat16(v2);
                }
            }
        }
    }
}

// ---------------- GEMM2: 256x128 tile, BK=32, 4-buffer counted-vmcnt pipeline ----------------
// ys[slot,:] = hmid[slot,:] @ w2t[e]^T + b2[e]  (f32 out)
__global__ __launch_bounds__(512) void gemm2_kernel(const bf16* __restrict__ hmid, const bf16* __restrict__ w2t,
        const float* __restrict__ b2, const int* __restrict__ offs, float* __restrict__ ys,
        const int* __restrict__ tmr, const int* __restrict__ tme, const int* __restrict__ tmn) {
    __shared__ bf16 As[4 * 256 * 32];   // 64 KB
    __shared__ bf16 Bs[4 * 128 * 32];   // 32 KB
    int nwg = gridDim.x;                 // 576, %8==0
    int orig = blockIdx.x;
    int wg = (orig & 7) * (nwg >> 3) + (orig >> 3);
    int nt = wg / TMAX, tidx = wg % TMAX;
    if (tidx >= tmn[0]) return;
    int e = tme[tidx], row0 = tmr[tidx], s1 = offs[e + 1];
    int n0 = nt * 128;
    int t = threadIdx.x;
    int lane = t & 63, w = t >> 6;
    const bf16* w2e = w2t + (size_t)e * HD * FHD;
    int rs = t >> 2, g = t & 3;
    int swz = (g ^ ((rs >> 1) & 3)) * 8;
    int ar0 = row0 + rs;       if (ar0 >= s1) ar0 = s1 - 1;
    int ar1 = row0 + rs + 128; if (ar1 >= s1) ar1 = s1 - 1;
    const bf16* srcA0 = hmid + (size_t)ar0 * FHD + swz;
    const bf16* srcA1 = hmid + (size_t)ar1 * FHD + swz;
    const bf16* srcB0 = w2e + (size_t)(n0 + rs) * FHD + swz;   // B: 128 rows, single issue
    int dstA0 = w * 512;
    int dstA1 = 4096 + w * 512;
    int dstB  = w * 512;
    int wr = w >> 1, wc = w & 1;         // 4M x 2N waves, per-wave 64x64
    int lr = lane & 15, lk = (lane >> 4) * 8;
    int offA[4], offB[4];
#pragma unroll
    for (int m = 0; m < 4; ++m) { int row = wr * 64 + m * 16 + lr; offA[m] = row * 32 + (lk ^ (8 * ((row >> 1) & 3))); }
#pragma unroll
    for (int n = 0; n < 4; ++n) { int row = wc * 64 + n * 16 + lr; offB[n] = row * 32 + (lk ^ (8 * ((row >> 1) & 3))); }
    f32x4 acc[4][4] = {};
#pragma unroll
    for (int kt = 0; kt < 3; ++kt) {
        int boA = kt * 8192, boB = kt * 4096, ko = kt * 32;
        gload_lds16(srcA0 + ko, &As[boA + dstA0]);
        gload_lds16(srcA1 + ko, &As[boA + dstA1]);
        gload_lds16(srcB0 + ko, &Bs[boB + dstB]);
    }
    asm volatile("s_waitcnt vmcnt(6)" ::: "memory");
    __builtin_amdgcn_s_barrier();
    for (int kt = 0; kt < FHD / 32; ++kt) {
        const bf16* Ab = &As[(kt & 3) * 8192];
        const bf16* Bb = &Bs[(kt & 3) * 4096];
        s16x8 aF[4], bF[4];
#pragma unroll
        for (int m = 0; m < 4; ++m) aF[m] = *reinterpret_cast<const s16x8*>(&Ab[offA[m]]);
#pragma unroll
        for (int n = 0; n < 4; ++n) bF[n] = *reinterpret_cast<const s16x8*>(&Bb[offB[n]]);
        int kt3 = kt + 3; if (kt3 >= FHD / 32) kt3 -= FHD / 32;
        int boA = (kt3 & 3) * 8192, boB = (kt3 & 3) * 4096, ko = kt3 * 32;
        gload_lds16(srcA0 + ko, &As[boA + dstA0]);
        gload_lds16(srcA1 + ko, &As[boA + dstA1]);
        gload_lds16(srcB0 + ko, &Bs[boB + dstB]);
        asm volatile("s_waitcnt vmcnt(6)" ::: "memory");
        __builtin_amdgcn_s_barrier();
        __builtin_amdgcn_sched_barrier(0);
        __builtin_amdgcn_s_setprio(1);
#pragma unroll
        for (int m = 0; m < 4; ++m)
#pragma unroll
            for (int n = 0; n < 4; ++n)
                acc[m][n] = __builtin_amdgcn_mfma_f32_16x16x32_bf16(aF[m], bF[n], acc[m][n], 0, 0, 0);
        __builtin_amdgcn_s_setprio(0);
        __builtin_amdgcn_sched_barrier(0);
        __builtin_amdgcn_s_barrier();
    }
#pragma unroll
    for (int n = 0; n < 4; ++n) {
        int col = n0 + wc * 64 + n * 16 + lr;
        float bv = b2[(size_t)e * HD + col];
#pragma unroll
        for (int m = 0; m < 4; ++m) {
#pragma unroll
            for (int r = 0; r < 4; ++r) {
                int row = wr * 64 + m * 16 + (lane >> 4) * 4 + r;
                int slot = row0 + row;
                if (slot < s1) ys[(size_t)slot * HD + col] = acc[m][n][r] + bv;
            }
        }
    }
}

// out[t,:] = tw[slot0[t]] * ys[slot0[t],:] + tw[slot1[t]] * ys[slot1[t],:]
__global__ __launch_bounds__(256) void combine_kernel(const float* __restrict__ ys,
        const int* __restrict__ slot0, const int* __restrict__ slot1,
        const float* __restrict__ tw, float* __restrict__ out) {
    int t = blockIdx.x;
    int c = threadIdx.x * 4;
    int sa = slot0[t], sb = slot1[t];
    float wa = tw[sa], wb = tw[sb];
    float4 a = *reinterpret_cast<const float4*>(&ys[(size_t)sa * HD + c]);
    float4 b = *reinterpret_cast<const float4*>(&ys[(size_t)sb * HD + c]);
    float4 o;
    o.x = wa * a.x + wb * b.x; o.y = wa * a.y + wb * b.y;
    o.z = wa * a.z + wb * b.z; o.w = wa * a.w + wb * b.w;
    *reinterpret_cast<float4*>(&out[(size_t)t * HD + c]) = o;
}

extern "C" void kernel_launch(void* const* d_in, const int* in_sizes, int n_in,
                              void* d_out, int out_size, void* d_ws, size_t ws_size,
                              hipStream_t stream) {
    const float* x  = (const float*)d_in[0];
    const float* rw = (const float*)d_in[1];
    const float* rb = (const float*)d_in[2];
    const float* w1 = (const float*)d_in[3];
    const float* b1 = (const float*)d_in[4];
    const float* w2 = (const float*)d_in[5];
    const float* b2 = (const float*)d_in[6];
    float* out = (float*)d_out;
    char* ws = (char*)d_ws;

    int*   counts  = (int*)(ws + OFF_COUNTS);
    int*   cursor  = (int*)(ws + OFF_CURSOR);
    int*   offs    = (int*)(ws + OFF_OFFS);
    int*   e0a     = (int*)(ws + OFF_E0);
    int*   e1a     = (int*)(ws + OFF_E1);
    float* w0a     = (float*)(ws + OFF_W0);
    float* w1a     = (float*)(ws + OFF_W1);
    int*   slot0   = (int*)(ws + OFF_S0);
    int*   slot1   = (int*)(ws + OFF_S1);
    int*   tid_arr = (int*)(ws + OFF_TID);
    float* tw_arr  = (float*)(ws + OFF_TW);
    int*   tmr     = (int*)(ws + OFF_TMR);
    int*   tme     = (int*)(ws + OFF_TME);
    int*   tmn     = (int*)(ws + OFF_TMN);
    bf16*  xbf     = (bf16*)(ws + OFF_XBF);
    bf16*  w1t     = (bf16*)(ws + OFF_W1T);
    bf16*  w2t     = (bf16*)(ws + OFF_W2T);
    bf16*  hmid    = (bf16*)(ws + OFF_HMID);
    float* ys      = (float*)(ws + OFF_YS);

    hipMemsetAsync(counts, 0, 64, stream);

    cast_x_kernel<<<TT * HD / 2048, 256, 0, stream>>>(x, xbf);
    transpose_cast_kernel<<<NE * (HD / 64) * (FHD / 64), 256, 0, stream>>>(w1, w1t, HD, FHD);
    transpose_cast_kernel<<<NE * (FHD / 64) * (HD / 64), 256, 0, stream>>>(w2, w2t, FHD, HD);
    router_kernel<<<TT / 4, 256, 0, stream>>>(x, rw, rb, e0a, e1a, w0a, w1a, counts);
    scan_offsets_kernel<<<1, 64, 0, stream>>>(counts, offs, cursor, tmr, tme, tmn);
    scatter_kernel<<<TT / 256, 256, 0, stream>>>(e0a, e1a, w0a, w1a, cursor, tid_arr, tw_arr, slot0, slot1);
    gemm1_kernel<<<(FHD / 256) * TMAX, 512, 0, stream>>>(xbf, w1t, b1, offs, tid_arr, hmid, tmr, tme, tmn);
    gemm2_kernel<<<(HD / 128) * TMAX, 512, 0, stream>>>(hmid, w2t, b2, offs, ys, tmr, tme, tmn);
    combine_kernel<<<TT, 256, 0, stream>>>(ys, slot0, slot1, tw_arr, out);
}